// Round 1
// baseline (192.925 us; speedup 1.0000x reference)
//
#include <hip/hip_runtime.h>
#include <math.h>

// VAE loss: anneal * mean_n(KLD_n) + mean_n(NLL_n)
//   KLD_n = sum_d 0.5*(-lv + exp(lv) + mu^2 - 1)
//   NLL_n = logsumexp(row_n) - row_n[y_n]   (log_softmax gather, online 1-pass)
// N=8192 rows, V=32000 cols (fp32, 1.05 GB -> memory bound), LATENT=64.

#define N_ROWS 8192
#define V_COLS 32000
#define LATENT_D 64

__device__ __forceinline__ void combine_ms(float& m, float& s, float m2, float s2) {
    float M = fmaxf(m, m2);
    // exp(-inf)=0 so the m=-inf initial state combines safely
    s = s * __expf(m - M) + s2 * __expf(m2 - M);
    m = M;
}

__global__ __launch_bounds__(256) void vae_row_kernel(
    const float* __restrict__ dec,      // [N, V]
    const float* __restrict__ mu,       // [N, 64]
    const float* __restrict__ logvar,   // [N, 64]
    const int*   __restrict__ y,        // [N]
    const float* __restrict__ anneal,   // [1]
    float*       __restrict__ partial)  // [N] (d_ws)
{
    const int n = blockIdx.x;
    const int t = threadIdx.x;
    const float* row = dec + (size_t)n * V_COLS;
    const float4* row4 = (const float4*)row;   // 32000 % 4 == 0, 16B-aligned rows

    // ---- one-pass online softmax stats over this thread's strided chunk ----
    float m = -INFINITY, s = 0.0f;
    for (int i = t; i < V_COLS / 4; i += 256) {
        float4 v = row4[i];
        float lm = fmaxf(fmaxf(v.x, v.y), fmaxf(v.z, v.w));
        if (lm > m) { s *= __expf(m - lm); m = lm; }  // rare after warm-up
        s += __expf(v.x - m) + __expf(v.y - m)
           + __expf(v.z - m) + __expf(v.w - m);
    }

    // ---- wave (64-lane) butterfly reduce of (m, s) ----
    #pragma unroll
    for (int off = 1; off < 64; off <<= 1) {
        float m2 = __shfl_xor(m, off, 64);
        float s2 = __shfl_xor(s, off, 64);
        combine_ms(m, s, m2, s2);
    }

    // ---- cross-wave (4 waves) via LDS ----
    __shared__ float sm[4], ss[4];
    __shared__ float snll;
    const int wave = t >> 6, lane = t & 63;
    if (lane == 0) { sm[wave] = m; ss[wave] = s; }
    __syncthreads();
    if (t == 0) {
        float M = sm[0], S = ss[0];
        #pragma unroll
        for (int w = 1; w < 4; ++w) combine_ms(M, S, sm[w], ss[w]);
        float xy = row[y[n]];                 // gather the true-class logit
        snll = (M + __logf(S)) - xy;          // -log_softmax(row)[y]
    }
    __syncthreads();

    // ---- fused per-row KLD over the 64 latent dims (wave 0) ----
    if (t < 64) {
        float lv = logvar[n * LATENT_D + t];
        float mq = mu[n * LATENT_D + t];
        float k = 0.5f * (-lv + __expf(lv) + mq * mq - 1.0f);
        #pragma unroll
        for (int off = 1; off < 64; off <<= 1)
            k += __shfl_xor(k, off, 64);
        if (t == 0)
            partial[n] = anneal[0] * k + snll;
    }
}

__global__ __launch_bounds__(256) void vae_reduce_kernel(
    const float* __restrict__ partial, float* __restrict__ out)
{
    const int t = threadIdx.x;
    float s = 0.0f;
    for (int i = t; i < N_ROWS; i += 256) s += partial[i];
    #pragma unroll
    for (int off = 1; off < 64; off <<= 1) s += __shfl_xor(s, off, 64);
    __shared__ float ws[4];
    const int wave = t >> 6, lane = t & 63;
    if (lane == 0) ws[wave] = s;
    __syncthreads();
    if (t == 0)
        out[0] = (ws[0] + ws[1] + ws[2] + ws[3]) / (float)N_ROWS;
}

extern "C" void kernel_launch(void* const* d_in, const int* in_sizes, int n_in,
                              void* d_out, int out_size, void* d_ws, size_t ws_size,
                              hipStream_t stream) {
    const float* dec    = (const float*)d_in[0];
    const float* mu     = (const float*)d_in[1];
    const float* logvar = (const float*)d_in[2];
    const int*   y      = (const int*)d_in[3];
    const float* anneal = (const float*)d_in[4];
    float* out = (float*)d_out;
    float* partial = (float*)d_ws;   // 8192 floats = 32 KB

    vae_row_kernel<<<N_ROWS, 256, 0, stream>>>(dec, mu, logvar, y, anneal, partial);
    vae_reduce_kernel<<<1, 256, 0, stream>>>(partial, out);
}

// Round 2
// 190.378 us; speedup vs baseline: 1.0134x; 1.0134x over previous
//
#include <hip/hip_runtime.h>
#include <math.h>

// VAE loss: anneal * mean_n(KLD_n) + mean_n(NLL_n)
//   KLD_n = sum_d 0.5*(-lv + exp(lv) + mu^2 - 1)
//   NLL_n = logsumexp(row_n) - row_n[y_n]
// N=8192 rows, V=32000 fp32 cols (1.05 GB -> memory bound, floor ~167 us).
//
// Block = 320 threads (5 waves): 32000/4 float4 / 320 = 25 exact iterations,
// no bounds check. Branchless online-softmax update for clean unrolling.

#define N_ROWS 8192
#define V_COLS 32000
#define LATENT_D 64
#define THREADS 320        // 5 waves
#define ITERS 25           // (V_COLS/4) / THREADS, exact

__device__ __forceinline__ void combine_ms(float& m, float& s, float m2, float s2) {
    float M = fmaxf(m, m2);
    s = s * __expf(m - M) + s2 * __expf(m2 - M);   // exp(-inf)=0 handles init
    m = M;
}

__global__ __launch_bounds__(THREADS) void vae_row_kernel(
    const float* __restrict__ dec,      // [N, V]
    const float* __restrict__ mu,       // [N, 64]
    const float* __restrict__ logvar,   // [N, 64]
    const int*   __restrict__ y,        // [N]
    const float* __restrict__ anneal,   // [1]
    float*       __restrict__ partial)  // [N] (d_ws)
{
    const int n = blockIdx.x;
    const int t = threadIdx.x;
    const float* row = dec + (size_t)n * V_COLS;
    const float4* row4 = (const float4*)row;

    // Issue the true-class gather + anneal load EARLY so the ~900cy HBM-miss
    // latency hides under the 25-iteration streaming loop (t==0 only uses them).
    float xy = 0.0f, ann = 0.0f;
    if (t == 0) { xy = row[y[n]]; ann = anneal[0]; }

    // ---- one-pass branchless online softmax over this thread's chunk ----
    float m = -INFINITY, s = 0.0f;
    #pragma unroll 5
    for (int j = 0; j < ITERS; ++j) {
        float4 v = row4[t + j * THREADS];
        float lm = fmaxf(fmaxf(v.x, v.y), fmaxf(v.z, v.w));
        float M  = fmaxf(m, lm);
        s = s * __expf(m - M)
          + __expf(v.x - M) + __expf(v.y - M)
          + __expf(v.z - M) + __expf(v.w - M);
        m = M;
    }

    // ---- wave (64-lane) butterfly reduce of (m, s) ----
    #pragma unroll
    for (int off = 1; off < 64; off <<= 1) {
        float m2 = __shfl_xor(m, off, 64);
        float s2 = __shfl_xor(s, off, 64);
        combine_ms(m, s, m2, s2);
    }

    // ---- fused per-row KLD over the 64 latent dims (wave 0, independent) ----
    float k = 0.0f;
    if (t < 64) {
        float lv = logvar[n * LATENT_D + t];
        float mq = mu[n * LATENT_D + t];
        k = 0.5f * (-lv + __expf(lv) + mq * mq - 1.0f);
        #pragma unroll
        for (int off = 1; off < 64; off <<= 1)
            k += __shfl_xor(k, off, 64);
    }

    // ---- cross-wave (5 waves) combine via LDS, single sync ----
    __shared__ float sm[5], ss[5];
    const int wave = t >> 6, lane = t & 63;
    if (lane == 0) { sm[wave] = m; ss[wave] = s; }
    __syncthreads();
    if (t == 0) {
        float M = sm[0], S = ss[0];
        #pragma unroll
        for (int w = 1; w < 5; ++w) combine_ms(M, S, sm[w], ss[w]);
        float nll = (M + __logf(S)) - xy;      // -log_softmax(row)[y]
        partial[n] = ann * k + nll;
    }
}

__global__ __launch_bounds__(256) void vae_reduce_kernel(
    const float* __restrict__ partial, float* __restrict__ out)
{
    const int t = threadIdx.x;
    float s = 0.0f;
    for (int i = t; i < N_ROWS; i += 256) s += partial[i];
    #pragma unroll
    for (int off = 1; off < 64; off <<= 1) s += __shfl_xor(s, off, 64);
    __shared__ float ws[4];
    const int wave = t >> 6, lane = t & 63;
    if (lane == 0) ws[wave] = s;
    __syncthreads();
    if (t == 0)
        out[0] = (ws[0] + ws[1] + ws[2] + ws[3]) / (float)N_ROWS;
}

extern "C" void kernel_launch(void* const* d_in, const int* in_sizes, int n_in,
                              void* d_out, int out_size, void* d_ws, size_t ws_size,
                              hipStream_t stream) {
    const float* dec    = (const float*)d_in[0];
    const float* mu     = (const float*)d_in[1];
    const float* logvar = (const float*)d_in[2];
    const int*   y      = (const int*)d_in[3];
    const float* anneal = (const float*)d_in[4];
    float* out = (float*)d_out;
    float* partial = (float*)d_ws;   // 8192 floats = 32 KB

    vae_row_kernel<<<N_ROWS, THREADS, 0, stream>>>(dec, mu, logvar, y, anneal, partial);
    vae_reduce_kernel<<<1, 256, 0, stream>>>(partial, out);
}